// Round 1
// 271.211 us; speedup vs baseline: 1.0546x; 1.0546x over previous
//
#include <hip/hip_runtime.h>
#include <cmath>

#define BB 8
#define CC 256
#define CQ 64
#define NN 4096
constexpr float INV_N = 1.0f / 4096.0f;

typedef __attribute__((ext_vector_type(8))) short short8;
typedef __attribute__((ext_vector_type(4))) short short4v;
typedef __attribute__((ext_vector_type(4))) float float4v;

__device__ __forceinline__ short f2bf(float f) {
  union { float f; unsigned u; } x; x.f = f;
  unsigned r = x.u + 0x7fffu + ((x.u >> 16) & 1u);
  return (short)(r >> 16);
}

// ---------------------------------------------------------------------------
// One-time fp32 -> bf16 conversion of all conv weights into workspace.
// Removes per-block (512x redundant) weight conversion from qkv/attn.
// Regions in float4 units: wq 4096 | wk 4096 | wv 16384 | wg 16384 = 40960.
// grid 160 x 256 threads, one float4 per thread.
// ---------------------------------------------------------------------------
__global__ void wconv_kernel(const float* __restrict__ wq,
                             const float* __restrict__ wk,
                             const float* __restrict__ wv,
                             const float* __restrict__ wg,
                             short* __restrict__ wqb, short* __restrict__ wkb,
                             short* __restrict__ wvb, short* __restrict__ wgb) {
  const int t = blockIdx.x * 256 + threadIdx.x;
  const float* src;
  short* dst;
  int idx;
  if (t < 4096)        { src = wq; dst = wqb; idx = t; }
  else if (t < 8192)   { src = wk; dst = wkb; idx = t - 4096; }
  else if (t < 24576)  { src = wv; dst = wvb; idx = t - 8192; }
  else                 { src = wg; dst = wgb; idx = t - 24576; }
  const float4 v = *reinterpret_cast<const float4*>(&src[(size_t)idx * 4]);
  short4v o;
  o[0] = f2bf(v.x); o[1] = f2bf(v.y); o[2] = f2bf(v.z); o[3] = f2bf(v.w);
  *reinterpret_cast<short4v*>(&dst[(size_t)idx * 4]) = o;
}

// ---------------------------------------------------------------------------
// Fused q/k/v conv1x1 via bf16 MFMA. Reads x once, stages xt[n][c] bf16 in
// LDS, loops 6 chunks of 64 output channels (q | k | v0..v3).
// Weights pre-converted to bf16 (wconv_kernel): one short8 load per kk,
// prefetched one step ahead.
// grid (B, NN/64) so flat id % 8 == b -> each XCD owns one batch (L2 fit;
// writes land in the XCD L2 that attn_kernel reads from).
// ---------------------------------------------------------------------------
__global__ __launch_bounds__(256, 2) void qkv_kernel(
    const float* __restrict__ X,
    const short* __restrict__ wqb, const float* __restrict__ bq,
    const short* __restrict__ wkb, const float* __restrict__ bk,
    const short* __restrict__ wvb, const float* __restrict__ bv,
    short* __restrict__ qt, short* __restrict__ kt, short* __restrict__ vbf) {
  __shared__ short xt[64 * 272];   // [n][c] bf16, stride 272 (16B-aligned rows)
  __shared__ short Os[64 * 72];    // v-output staging [o][n]
  const int tid = threadIdx.x;
  const int wid = tid >> 6;
  const int lane = tid & 63, quad = lane >> 4, l16 = lane & 15;
  const int b = blockIdx.x, n0 = blockIdx.y * 64;

  // stage x tile -> xt[n][c] bf16 (transpose, fp32->bf16)
#pragma unroll 4
  for (int p = 0; p < 16; ++p) {
    const int idx = p * 256 + tid;
    const int c = idx >> 4;
    const int n4 = (idx & 15) * 4;
    const float4 x4 = *reinterpret_cast<const float4*>(
        &X[((size_t)b * CC + c) * NN + n0 + n4]);
    xt[(n4 + 0) * 272 + c] = f2bf(x4.x);
    xt[(n4 + 1) * 272 + c] = f2bf(x4.y);
    xt[(n4 + 2) * 272 + c] = f2bf(x4.z);
    xt[(n4 + 3) * 272 + c] = f2bf(x4.w);
  }
  __syncthreads();

  for (int ch = 0; ch < 6; ++ch) {
    const short* W; const float* bias; int obase;
    if (ch == 0)      { W = wqb; bias = bq; obase = 0; }
    else if (ch == 1) { W = wkb; bias = bk; obase = 0; }
    else { W = wvb + (size_t)(ch - 2) * 64 * CC; bias = bv + (ch - 2) * 64; obase = (ch - 2) * 64; }

    float4v acc[4];
#pragma unroll
    for (int tm = 0; tm < 4; ++tm) acc[tm] = float4v{0.f, 0.f, 0.f, 0.f};

    const short* wrow = &W[(size_t)(wid * 16 + l16) * CC + quad * 8];
    short8 a_cur = *reinterpret_cast<const short8*>(wrow);
#pragma unroll
    for (int kk = 0; kk < 8; ++kk) {
      short8 a_nxt = a_cur;
      if (kk < 7) a_nxt = *reinterpret_cast<const short8*>(wrow + (kk + 1) * 32);
#pragma unroll
      for (int tm = 0; tm < 4; ++tm) {
        const short8 bfrag = *reinterpret_cast<const short8*>(
            &xt[(tm * 16 + l16) * 272 + kk * 32 + quad * 8]);
        acc[tm] = __builtin_amdgcn_mfma_f32_16x16x32_bf16(a_cur, bfrag, acc[tm], 0, 0, 0);
      }
      a_cur = a_nxt;
    }

    // C layout: row o_local = wid*16 + quad*4 + r, col n_local = tm*16 + l16
    if (ch < 2) {
      short* dst = (ch == 0) ? qt : kt;
#pragma unroll
      for (int tm = 0; tm < 4; ++tm) {
        short4v pk;
#pragma unroll
        for (int r = 0; r < 4; ++r)
          pk[r] = f2bf(acc[tm][r] + bias[wid * 16 + quad * 4 + r]);
        *reinterpret_cast<short4v*>(
            &dst[((size_t)b * NN + n0 + tm * 16 + l16) * 64 + wid * 16 + quad * 4]) = pk;
      }
    } else {
      __syncthreads();  // previous chunk's Os reads complete
#pragma unroll
      for (int tm = 0; tm < 4; ++tm)
#pragma unroll
        for (int r = 0; r < 4; ++r)
          Os[(wid * 16 + quad * 4 + r) * 72 + tm * 16 + l16] =
              f2bf(acc[tm][r] + bias[wid * 16 + quad * 4 + r]);
      __syncthreads();
      const int o = tid >> 2, ng = (tid & 3) * 16;
      const short8 s0 = *reinterpret_cast<const short8*>(&Os[o * 72 + ng]);
      const short8 s1 = *reinterpret_cast<const short8*>(&Os[o * 72 + ng + 8]);
      short* vp = &vbf[((size_t)b * CC + obase + o) * NN + n0 + ng];
      *reinterpret_cast<short8*>(vp) = s0;
      *reinterpret_cast<short8*>(vp + 8) = s1;
    }
  }
}

// ---------------------------------------------------------------------------
// Fused MFMA attention + gamma conv, v3:
//  - grid (B, NN/64): flat id % 8 == b -> per-XCD working set = one batch
//    (qt+kt+vbf = 3 MB < 4 MB XCD L2) instead of 24 MB thrash
//  - v A-frags double-buffered ONE ITERATION ahead (like q) -> ~1.5 iters of
//    latency slack instead of ~0.3
//  - gamma weights pre-converted bf16 (no per-block f2bf in epilogue)
//  - Es double-buffered -> ONE barrier per iteration
// 256 threads (4 waves).
// ---------------------------------------------------------------------------
__global__ __launch_bounds__(256, 2) void attn_kernel(
    const short* __restrict__ qt, const short* __restrict__ kt,
    const short* __restrict__ vbf, const short* __restrict__ wgb,
    const float* __restrict__ bg, float* __restrict__ out) {
  __shared__ short smem[16896];   // 33792 B
  short* Es0 = smem;              // [64 m][72 n]
  short* Es1 = smem + 4608;
  short* Outs = smem;             // [64 m][264 c] epilogue alias

  const int tid = threadIdx.x;
  const int wid = tid >> 6;
  const int lane = tid & 63, quad = lane >> 4, l16 = lane & 15;
  const int b = blockIdx.x, m0 = blockIdx.y * 64;

  // k fragments: resident in registers for the whole kernel
  short8 bkf[4][2];
#pragma unroll
  for (int tm = 0; tm < 4; ++tm)
#pragma unroll
    for (int kk = 0; kk < 2; ++kk)
      bkf[tm][kk] = *reinterpret_cast<const short8*>(
          &kt[((size_t)b * NN + m0 + tm * 16 + l16) * 64 + kk * 32 + quad * 8]);

  const short* qrow = &qt[((size_t)b * NN + wid * 16 + l16) * 64 + quad * 8];
  const short* vrow[4];
#pragma unroll
  for (int tc = 0; tc < 4; ++tc)
    vrow[tc] = &vbf[((size_t)b * CC + wid * 64 + tc * 16 + l16) * NN + quad * 8];

  float4v acc[4][4];
#pragma unroll
  for (int i = 0; i < 4; ++i)
#pragma unroll
    for (int j = 0; j < 4; ++j) acc[i][j] = float4v{0.f, 0.f, 0.f, 0.f};

  // prefetch iter-0 q and v fragments
  short8 aq0 = *reinterpret_cast<const short8*>(qrow);
  short8 aq1 = *reinterpret_cast<const short8*>(qrow + 32);
  short8 av0[4][2], av1[4][2];
#pragma unroll
  for (int tc = 0; tc < 4; ++tc) {
    av0[tc][0] = *reinterpret_cast<const short8*>(vrow[tc]);
    av0[tc][1] = *reinterpret_cast<const short8*>(vrow[tc] + 32);
  }

  // avc: this iter's v-frags (loaded one iter ago); avn: next iter's, issued
  // here, waited on only at next iter's PV. Rotation via alternating calls
  // keeps everything statically indexed (no reg<->scratch).
  auto body = [&](int it, short8 (&avc)[4][2], short8 (&avn)[4][2]) {
    short* Esw = (it & 1) ? Es1 : Es0;
    const int nbn = (it + 1) * 64;

    // next iter's v fragments — issued early (reads past vbf end at it=63
    // land in the bf16-weight workspace region; values unused)
#pragma unroll
    for (int tc = 0; tc < 4; ++tc) {
      avn[tc][0] = *reinterpret_cast<const short8*>(vrow[tc] + nbn);
      avn[tc][1] = *reinterpret_cast<const short8*>(vrow[tc] + nbn + 32);
    }

    // S = q^T k (K=64 via two MFMAs per m-tile)
    float4v s[4];
#pragma unroll
    for (int tm = 0; tm < 4; ++tm) {
      float4v t = {0.f, 0.f, 0.f, 0.f};
      t = __builtin_amdgcn_mfma_f32_16x16x32_bf16(aq0, bkf[tm][0], t, 0, 0, 0);
      t = __builtin_amdgcn_mfma_f32_16x16x32_bf16(aq1, bkf[tm][1], t, 0, 0, 0);
      s[tm] = t;
    }

    // prefetch next iter's q fragments (spills into kt region at the end —
    // allocated workspace, values unused)
    const short8 aq0n = *reinterpret_cast<const short8*>(qrow + (size_t)nbn * 64);
    const short8 aq1n = *reinterpret_cast<const short8*>(qrow + (size_t)nbn * 64 + 32);

    // elu/N -> Es (C layout: m = tm*16+l16, n = wid*16+quad*4+r)
#pragma unroll
    for (int tm = 0; tm < 4; ++tm) {
      short4v pk;
#pragma unroll
      for (int r = 0; r < 4; ++r) {
        float sv = s[tm][r];
        sv = (sv > 0.f) ? sv : (__expf(sv) - 1.f);
        pk[r] = f2bf(sv * INV_N);
      }
      *reinterpret_cast<short4v*>(
          &Esw[(tm * 16 + l16) * 72 + wid * 16 + quad * 4]) = pk;
    }
    __syncthreads();

    // PV: acc[c-tile][m-tile] += V E   (uses avc, loaded one iter ago)
#pragma unroll
    for (int tm = 0; tm < 4; ++tm) {
      const short8 be0 = *reinterpret_cast<const short8*>(
          &Esw[(tm * 16 + l16) * 72 + quad * 8]);
      const short8 be1 = *reinterpret_cast<const short8*>(
          &Esw[(tm * 16 + l16) * 72 + 32 + quad * 8]);
#pragma unroll
      for (int tc = 0; tc < 4; ++tc) {
        acc[tc][tm] = __builtin_amdgcn_mfma_f32_16x16x32_bf16(avc[tc][0], be0, acc[tc][tm], 0, 0, 0);
        acc[tc][tm] = __builtin_amdgcn_mfma_f32_16x16x32_bf16(avc[tc][1], be1, acc[tc][tm], 0, 0, 0);
      }
    }
    aq0 = aq0n; aq1 = aq1n;
  };

  for (int it = 0; it < 64; it += 2) {
    body(it, av0, av1);
    body(it + 1, av1, av0);
  }

  // ---- epilogue: gamma conv via MFMA (bf16 weights, no conversion) ----
  __syncthreads();
#pragma unroll
  for (int tc = 0; tc < 4; ++tc)
#pragma unroll
    for (int tm = 0; tm < 4; ++tm) {
      short4v pk;
#pragma unroll
      for (int r = 0; r < 4; ++r) pk[r] = f2bf(acc[tc][tm][r]);
      *reinterpret_cast<short4v*>(
          &Outs[(tm * 16 + l16) * 264 + wid * 64 + tc * 16 + quad * 4]) = pk;
    }
  __syncthreads();

#pragma unroll
  for (int i = 0; i < 4; ++i)
#pragma unroll
    for (int j = 0; j < 4; ++j) acc[i][j] = float4v{0.f, 0.f, 0.f, 0.f};

  for (int ks8 = 0; ks8 < 8; ++ks8) {
    short8 ag[4];
#pragma unroll
    for (int to = 0; to < 4; ++to)
      ag[to] = *reinterpret_cast<const short8*>(
          &wgb[(size_t)(wid * 64 + to * 16 + l16) * CC + ks8 * 32 + quad * 8]);
    short8 bo[4];
#pragma unroll
    for (int tm = 0; tm < 4; ++tm)
      bo[tm] = *reinterpret_cast<const short8*>(
          &Outs[(tm * 16 + l16) * 264 + ks8 * 32 + quad * 8]);
#pragma unroll
    for (int to = 0; to < 4; ++to)
#pragma unroll
      for (int tm = 0; tm < 4; ++tm)
        acc[to][tm] =
            __builtin_amdgcn_mfma_f32_16x16x32_bf16(ag[to], bo[tm], acc[to][tm], 0, 0, 0);
  }

#pragma unroll
  for (int to = 0; to < 4; ++to) {
#pragma unroll
    for (int r = 0; r < 4; ++r) {
      const int o = wid * 64 + to * 16 + quad * 4 + r;
      const float bgv = bg[o];
#pragma unroll
      for (int tm = 0; tm < 4; ++tm) {
        out[((size_t)b * CC + o) * NN + m0 + tm * 16 + l16] =
            acc[to][tm][r] + bgv;
      }
    }
  }
}

// ---------------------------------------------------------------------------
extern "C" void kernel_launch(void* const* d_in, const int* in_sizes, int n_in,
                              void* d_out, int out_size, void* d_ws,
                              size_t ws_size, hipStream_t stream) {
  const float* x  = (const float*)d_in[0];
  const float* wq = (const float*)d_in[1];
  const float* bq = (const float*)d_in[2];
  const float* wk = (const float*)d_in[3];
  const float* bk = (const float*)d_in[4];
  const float* wv = (const float*)d_in[5];
  const float* bv = (const float*)d_in[6];
  const float* wg = (const float*)d_in[7];
  const float* bg = (const float*)d_in[8];
  float* out = (float*)d_out;

  short* qt  = (short*)d_ws;                     // [B][N][64] bf16, 4 MB
  short* kt  = qt + (size_t)BB * NN * CQ;        // 4 MB
  short* vbf = kt + (size_t)BB * NN * CQ;        // [B][C][N] bf16, 16 MB
  short* wqb = vbf + (size_t)BB * CC * NN;       // bf16 weights, 320 KB total
  short* wkb = wqb + (size_t)CQ * CC;
  short* wvb = wkb + (size_t)CQ * CC;
  short* wgb = wvb + (size_t)CC * CC;

  wconv_kernel<<<dim3(160), 256, 0, stream>>>(wq, wk, wv, wg, wqb, wkb, wvb, wgb);
  qkv_kernel<<<dim3(BB, NN / 64), 256, 0, stream>>>(x, wqb, bq, wkb, bk, wvb, bv,
                                                    qt, kt, vbf);
  attn_kernel<<<dim3(BB, NN / 64), 256, 0, stream>>>(qt, kt, vbf, wgb, bg, out);
}